// Round 1
// baseline (179.278 us; speedup 1.0000x reference)
//
#include <hip/hip_runtime.h>
#include <stdint.h>

#define DI __device__ __forceinline__

typedef __attribute__((ext_vector_type(8))) short short8;
typedef __attribute__((ext_vector_type(4))) short short4v;
typedef __attribute__((ext_vector_type(4))) float f32x4;

DI float bf2f(unsigned short u){ union{unsigned int i; float f;} v; v.i = ((unsigned int)u)<<16; return v.f; }
DI unsigned short f2bf(float f){ union{float f; unsigned int i;} v; v.f=f; return (unsigned short)((v.i + 0x7fffu + ((v.i>>16)&1u))>>16); }
DI float siluf(float x){ return x/(1.f + __expf(-x)); }
DI f32x4 vzero(){ f32x4 z; z[0]=0.f;z[1]=0.f;z[2]=0.f;z[3]=0.f; return z; }
DI f32x4 vsplat(float x){ f32x4 z; z[0]=x;z[1]=x;z[2]=x;z[3]=x; return z; }

// ---------------- weight prep ----------------
struct PrepArgs {
  const float* W[6];
  const float* g[6];
  unsigned short* Wt[6];
  int C[6];
};

__global__ __launch_bounds__(256) void prep_transpose(PrepArgs a){
  int m = blockIdx.z;
  int C = a.C[m];
  int nt = C >> 5;
  if ((int)blockIdx.x >= nt || (int)blockIdx.y >= nt) return;
  __shared__ float tile[32][33];
  int col = threadIdx.x & 31;
  int rr  = threadIdx.x >> 5;
  const float* W = a.W[m];
  const float* g = a.g[m];
  #pragma unroll
  for (int p=0;p<4;++p){
    int r = rr + p*8;
    int cK = blockIdx.x*32 + r;
    int dN = blockIdx.y*32 + col;
    float v = W[(size_t)cK*C + dN];
    if (g) v *= g[cK];
    tile[r][col] = v;
  }
  __syncthreads();
  unsigned short* Wt = a.Wt[m];
  #pragma unroll
  for (int p=0;p<4;++p){
    int r = rr + p*8;
    int dN = blockIdx.y*32 + r;
    int cK = blockIdx.x*32 + col;
    Wt[(size_t)dN*C + cK] = f2bf(tile[col][r]);  // Wt[d][c] = g[c]*W[c][d]
  }
}

struct ColArgs {
  const float* W[4]; const float* g[4]; const float* b[4]; const float* extra[4];
  float* ocs[4]; float* obs[4]; int C[4];
};

__global__ __launch_bounds__(256) void prep_colsum(ColArgs a){
  int j = blockIdx.x;
  int C = a.C[j];
  int d = threadIdx.x;
  if (d >= C) return;
  const float* W = a.W[j]; const float* g = a.g[j]; const float* b = a.b[j];
  float cs = 0.f, bs = 0.f;
  for (int c=0;c<C;++c){
    float w = W[(size_t)c*C + d];
    cs += g[c]*w;
    bs += b[c]*w;
  }
  if (a.extra[j]) bs += a.extra[j][d];
  a.ocs[j][d] = cs;
  a.obs[j][d] = bs;
}

// ---------------- shared helpers ----------------
// LDS layout: row-major [rows][C] bf16, XOR-swizzled at 16B-chunk granularity:
// byte(row, chunk) = row*2C + ((chunk ^ (row&7))*16)

template<int C>
DI short8 readFrag(const short* S, int rowBase, int ks, int lane){
  int row = rowBase + (lane & 15);                 // rowBase multiple of 16 -> row&7 == lane&7
  int chunk = (ks*4 + ((lane>>4)&3)) ^ (lane & 7);
  return *(const short8*)((const char*)S + row*(2*C) + chunk*16);
}

// stage raw x (fp32, channel-major in global) into LDS bf16 [64 px][C], computing LN stats in fp32
template<int C>
DI void stageA_x(const float* __restrict__ xb, int strideC, short* As,
                 float* red, float* smean, float* srstd){
  int tid = threadIdx.x;
  int px = tid & 63, g = tid >> 6;            // px lane, channel-group
  float sum = 0.f, sq = 0.f;
  #pragma unroll
  for (int it=0; it<C/16; ++it){
    int cb = it*16 + g*4;
    float v0 = xb[(size_t)(cb+0)*strideC + px];
    float v1 = xb[(size_t)(cb+1)*strideC + px];
    float v2 = xb[(size_t)(cb+2)*strideC + px];
    float v3 = xb[(size_t)(cb+3)*strideC + px];
    sum += v0+v1+v2+v3;
    sq  += v0*v0+v1*v1+v2*v2+v3*v3;
    short4v pk;
    pk[0]=(short)f2bf(v0); pk[1]=(short)f2bf(v1); pk[2]=(short)f2bf(v2); pk[3]=(short)f2bf(v3);
    int chunk = cb >> 3;
    *(short4v*)((char*)As + px*(2*C) + ((chunk ^ (px&7))*16) + (cb&7)*2) = pk;
  }
  red[g*64 + px] = sum;
  red[256 + g*64 + px] = sq;
  __syncthreads();
  if (tid < 64){
    float s=0.f, q=0.f;
    #pragma unroll
    for (int gg=0; gg<4; ++gg){ s += red[gg*64+tid]; q += red[256+gg*64+tid]; }
    float m = s*(1.f/C);
    float var = fmaxf(q*(1.f/C) - m*m, 0.f);
    smean[tid] = m;
    srstd[tid] = rsqrtf(var + 1e-5f);
  }
  __syncthreads();
}

// copy bf16 row-major [ROWS][C] from global into swizzled LDS
template<int C, int ROWS>
DI void stageCopy(const unsigned short* __restrict__ src, short* dst){
  int tid = threadIdx.x;
  constexpr int CH = C/8;
  constexpr int IT = (ROWS*CH)/256;
  #pragma unroll
  for (int it=0; it<IT; ++it){
    int i = tid + it*256;
    int row = i / CH, ch = i % CH;
    short8 v = *(const short8*)(src + (size_t)row*C + ch*8);
    *(short8*)((char*)dst + row*(2*C) + ((ch ^ (row&7))*16)) = v;
  }
}

template<int C>
DI void mfmaLoop(const short* As, const short* Bs, f32x4 acc[2][4], int lane, int wr, int wc){
  #pragma unroll
  for (int ks=0; ks<C/32; ++ks){
    short8 a0 = readFrag<C>(As, wr*32 +  0, ks, lane);
    short8 a1 = readFrag<C>(As, wr*32 + 16, ks, lane);
    short8 b0 = readFrag<C>(Bs, wc*64 +  0, ks, lane);
    short8 b1 = readFrag<C>(Bs, wc*64 + 16, ks, lane);
    short8 b2 = readFrag<C>(Bs, wc*64 + 32, ks, lane);
    short8 b3 = readFrag<C>(Bs, wc*64 + 48, ks, lane);
    acc[0][0] = __builtin_amdgcn_mfma_f32_16x16x32_bf16(a0,b0,acc[0][0],0,0,0);
    acc[0][1] = __builtin_amdgcn_mfma_f32_16x16x32_bf16(a0,b1,acc[0][1],0,0,0);
    acc[0][2] = __builtin_amdgcn_mfma_f32_16x16x32_bf16(a0,b2,acc[0][2],0,0,0);
    acc[0][3] = __builtin_amdgcn_mfma_f32_16x16x32_bf16(a0,b3,acc[0][3],0,0,0);
    acc[1][0] = __builtin_amdgcn_mfma_f32_16x16x32_bf16(a1,b0,acc[1][0],0,0,0);
    acc[1][1] = __builtin_amdgcn_mfma_f32_16x16x32_bf16(a1,b1,acc[1][1],0,0,0);
    acc[1][2] = __builtin_amdgcn_mfma_f32_16x16x32_bf16(a1,b2,acc[1][2],0,0,0);
    acc[1][3] = __builtin_amdgcn_mfma_f32_16x16x32_bf16(a1,b3,acc[1][3],0,0,0);
  }
}

// ---------------- K1: cur_proj = LN(cur) @ Wcur ----------------
template<int C>
__global__ __launch_bounds__(256) void k1_curproj(
    const float* __restrict__ x, const unsigned short* __restrict__ Wt,
    const float* __restrict__ colsum, const float* __restrict__ bias,
    unsigned short* __restrict__ Pout, unsigned short* __restrict__ curT,
    int Npix, int HW){
  constexpr int T = 5;
  __shared__ __align__(16) short As[64*C];
  __shared__ __align__(16) short Bs[128*C];
  __shared__ float red[512];
  __shared__ float smean[64], srstd[64];

  int n0 = blockIdx.y*128;
  int px0 = blockIdx.x*64;
  int b = px0 / HW, hw0 = px0 % HW;
  const float* xb = x + ((size_t)b*C*T + (T-1))*HW + hw0;   // c=0, t=T-1

  stageCopy<C,128>(Wt + (size_t)n0*C, Bs);
  stageA_x<C>(xb, T*HW, As, red, smean, srstd);

  int tid = threadIdx.x, lane = tid&63, wid = tid>>6, wr = wid>>1, wc = wid&1, hi = lane>>4;
  f32x4 acc[2][4];
  #pragma unroll
  for (int i=0;i<2;++i)
    #pragma unroll
    for (int j=0;j<4;++j) acc[i][j] = vzero();
  mfmaLoop<C>(As, Bs, acc, lane, wr, wc);

  if (n0 == 0){  // write transposed raw cur (bf16) for K2's residual
    constexpr int CH = C/8;
    #pragma unroll
    for (int it=0; it<(64*CH)/256; ++it){
      int i = tid + it*256;
      int row = i/CH, ch = i%CH;
      short8 v = *(const short8*)((const char*)As + row*(2*C) + ((ch ^ (row&7))*16));
      *(short8*)(curT + (size_t)(px0+row)*C + ch*8) = v;
    }
  }

  #pragma unroll
  for (int nf=0; nf<4; ++nf){
    int d = n0 + wc*64 + nf*16 + (lane&15);
    float cs = colsum[d], bi = bias[d];
    #pragma unroll
    for (int mf=0; mf<2; ++mf){
      #pragma unroll
      for (int r=0; r<4; ++r){
        int pl = wr*32 + mf*16 + hi*4 + r;
        float P = srstd[pl]*(acc[mf][nf][r] - smean[pl]*cs) + bi;
        Pout[(size_t)(px0+pl)*C + d] = f2bf(P);
      }
    }
  }
}

// ---------------- K2: h = cur + silu(cur_proj + LN(ref_t)@Wref + bf) ----------------
template<int C>
__global__ __launch_bounds__(256) void k2_refproj(
    const float* __restrict__ x, const unsigned short* __restrict__ Wt,
    const float* __restrict__ colsum, const float* __restrict__ biasRf,
    const unsigned short* __restrict__ Pcur, const unsigned short* __restrict__ curT,
    unsigned short* __restrict__ hout, int Npix, int HW){
  constexpr int T = 5;
  __shared__ __align__(16) short As[64*C];
  __shared__ __align__(16) short Bs[128*C];
  __shared__ float red[512];
  __shared__ float smean[64], srstd[64];

  int n0 = blockIdx.y*128;
  int px0 = blockIdx.x*64;
  int t = blockIdx.z;
  int b = px0 / HW, hw0 = px0 % HW;
  const float* xb = x + ((size_t)b*C*T + t)*HW + hw0;

  stageCopy<C,128>(Wt + (size_t)n0*C, Bs);
  stageA_x<C>(xb, T*HW, As, red, smean, srstd);

  int tid = threadIdx.x, lane = tid&63, wid = tid>>6, wr = wid>>1, wc = wid&1, hi = lane>>4;
  f32x4 acc[2][4];
  #pragma unroll
  for (int i=0;i<2;++i)
    #pragma unroll
    for (int j=0;j<4;++j) acc[i][j] = vzero();
  mfmaLoop<C>(As, Bs, acc, lane, wr, wc);

  #pragma unroll
  for (int nf=0; nf<4; ++nf){
    int d = n0 + wc*64 + nf*16 + (lane&15);
    float cs = colsum[d], bi = biasRf[d];
    #pragma unroll
    for (int mf=0; mf<2; ++mf){
      #pragma unroll
      for (int r=0; r<4; ++r){
        int pl = wr*32 + mf*16 + hi*4 + r;
        size_t idx = (size_t)(px0+pl)*C + d;
        float pre = srstd[pl]*(acc[mf][nf][r] - smean[pl]*cs) + bi + bf2f(Pcur[idx]);
        float h = bf2f(curT[idx]) + siluf(pre);
        hout[(size_t)t*Npix*C + idx] = f2bf(h);
      }
    }
  }
}

// ---------------- K3: y_t = silu((h_t @ convw)*bns + bnb); out = max_t + mean_t ----------------
template<int C>
__global__ __launch_bounds__(256) void k3_conv(
    const unsigned short* __restrict__ h, const unsigned short* __restrict__ WtV,
    const float* __restrict__ bns, const float* __restrict__ bnb,
    float* __restrict__ out, int Npix, int HW){
  constexpr int PB = 133;
  constexpr int AsBytes = 64*C*2;
  constexpr int PoolBytes = 64*PB*4;
  constexpr int U = (AsBytes > PoolBytes) ? AsBytes : PoolBytes;
  __shared__ __align__(16) char uni[U];
  __shared__ __align__(16) short Bs[128*C];
  short* As = (short*)uni;
  float* pool = (float*)uni;

  int n0 = blockIdx.y*128;
  int px0 = blockIdx.x*64;
  int b = px0 / HW, hw0 = px0 % HW;
  int tid = threadIdx.x, lane = tid&63, wid = tid>>6, wr = wid>>1, wc = wid&1, hi = lane>>4;

  stageCopy<C,128>(WtV + (size_t)n0*C, Bs);

  f32x4 mx[2][4], sm[2][4];
  #pragma unroll
  for (int i=0;i<2;++i)
    #pragma unroll
    for (int j=0;j<4;++j){ mx[i][j] = vsplat(-3.0e38f); sm[i][j] = vzero(); }

  for (int t=0; t<4; ++t){
    __syncthreads();                      // t=0: Bs ready; t>0: prev reads of As done
    stageCopy<C,64>(h + ((size_t)t*Npix + px0)*C, As);
    __syncthreads();
    f32x4 acc[2][4];
    #pragma unroll
    for (int i=0;i<2;++i)
      #pragma unroll
      for (int j=0;j<4;++j) acc[i][j] = vzero();
    mfmaLoop<C>(As, Bs, acc, lane, wr, wc);
    #pragma unroll
    for (int nf=0; nf<4; ++nf){
      int d = n0 + wc*64 + nf*16 + (lane&15);
      float s_ = bns[d], b_ = bnb[d];
      #pragma unroll
      for (int mf=0; mf<2; ++mf){
        #pragma unroll
        for (int r=0; r<4; ++r){
          float y = siluf(acc[mf][nf][r]*s_ + b_);
          mx[mf][nf][r] = fmaxf(mx[mf][nf][r], y);
          sm[mf][nf][r] += y;
        }
      }
    }
  }

  __syncthreads();   // all MFMA reads of As done; reuse as pool buffer
  #pragma unroll
  for (int nf=0; nf<4; ++nf){
    int dl = wc*64 + nf*16 + (lane&15);
    #pragma unroll
    for (int mf=0; mf<2; ++mf){
      #pragma unroll
      for (int r=0; r<4; ++r){
        int pl = wr*32 + mf*16 + hi*4 + r;
        pool[pl*PB + dl] = mx[mf][nf][r] + 0.25f*sm[mf][nf][r];
      }
    }
  }
  __syncthreads();

  #pragma unroll
  for (int it=0; it<8; ++it){            // 64px * 128d / (256 thr * 4 floats)
    int i = tid + it*256;
    int dl = i >> 4;
    int pq = (i & 15) * 4;
    f32x4 vv;
    #pragma unroll
    for (int k=0;k<4;++k) vv[k] = pool[(pq+k)*PB + dl];
    *(f32x4*)(out + (size_t)(b*C + n0 + dl)*HW + hw0 + pq) = vv;
  }
}

// ---------------- host ----------------
extern "C" void kernel_launch(void* const* d_in, const int* in_sizes, int n_in,
                              void* d_out, int out_size, void* d_ws, size_t ws_size,
                              hipStream_t stream) {
  (void)in_sizes; (void)n_in; (void)out_size; (void)ws_size;
  const float* x2    = (const float*)d_in[0];
  const float* x1    = (const float*)d_in[1];
  const float* g2c   = (const float*)d_in[3];
  const float* b2c   = (const float*)d_in[4];
  const float* g2r   = (const float*)d_in[5];
  const float* b2r   = (const float*)d_in[6];
  const float* W2cur = (const float*)d_in[7];
  const float* W2ref = (const float*)d_in[8];
  const float* bias2 = (const float*)d_in[9];
  const float* convw2= (const float*)d_in[10];
  const float* bns2  = (const float*)d_in[11];
  const float* bnb2  = (const float*)d_in[12];
  const float* g1c   = (const float*)d_in[13];
  const float* b1c   = (const float*)d_in[14];
  const float* g1r   = (const float*)d_in[15];
  const float* b1r   = (const float*)d_in[16];
  const float* W1cur = (const float*)d_in[17];
  const float* W1ref = (const float*)d_in[18];
  const float* bias1 = (const float*)d_in[19];
  const float* convw1= (const float*)d_in[20];
  const float* bns1  = (const float*)d_in[21];
  const float* bnb1  = (const float*)d_in[22];

  const int C2 = 128, C1 = 256;
  const int NP2 = 8*64*64, NP1 = 8*32*32;   // 32768, 8192
  const int HW2 = 4096, HW1 = 1024;

  char* ws = (char*)d_ws;
  size_t off = 0;
  auto alloc = [&](size_t bytes){ size_t o = off; off = (off + bytes + 255) & ~(size_t)255; return o; };
  size_t oWtC2 = alloc((size_t)C2*C2*2), oWtR2 = alloc((size_t)C2*C2*2), oWtV2 = alloc((size_t)C2*C2*2);
  size_t oWtC1 = alloc((size_t)C1*C1*2), oWtR1 = alloc((size_t)C1*C1*2), oWtV1 = alloc((size_t)C1*C1*2);
  size_t oColC2 = alloc(C2*4), oBiasC2 = alloc(C2*4), oColR2 = alloc(C2*4), oBiasR2 = alloc(C2*4);
  size_t oColC1 = alloc(C1*4), oBiasC1 = alloc(C1*4), oColR1 = alloc(C1*4), oBiasR1 = alloc(C1*4);
  size_t oP2  = alloc((size_t)NP2*C2*2);
  size_t oCT2 = alloc((size_t)NP2*C2*2);
  size_t oH2  = alloc((size_t)4*NP2*C2*2);
  size_t oP1  = alloc((size_t)NP1*C1*2);
  size_t oCT1 = alloc((size_t)NP1*C1*2);
  size_t oH1  = alloc((size_t)4*NP1*C1*2);

  unsigned short* WtC2 = (unsigned short*)(ws + oWtC2);
  unsigned short* WtR2 = (unsigned short*)(ws + oWtR2);
  unsigned short* WtV2 = (unsigned short*)(ws + oWtV2);
  unsigned short* WtC1 = (unsigned short*)(ws + oWtC1);
  unsigned short* WtR1 = (unsigned short*)(ws + oWtR1);
  unsigned short* WtV1 = (unsigned short*)(ws + oWtV1);
  float* ColC2 = (float*)(ws + oColC2); float* BiasC2 = (float*)(ws + oBiasC2);
  float* ColR2 = (float*)(ws + oColR2); float* BiasR2 = (float*)(ws + oBiasR2);
  float* ColC1 = (float*)(ws + oColC1); float* BiasC1 = (float*)(ws + oBiasC1);
  float* ColR1 = (float*)(ws + oColR1); float* BiasR1 = (float*)(ws + oBiasR1);
  unsigned short* P2  = (unsigned short*)(ws + oP2);
  unsigned short* CT2 = (unsigned short*)(ws + oCT2);
  unsigned short* H2  = (unsigned short*)(ws + oH2);
  unsigned short* P1  = (unsigned short*)(ws + oP1);
  unsigned short* CT1 = (unsigned short*)(ws + oCT1);
  unsigned short* H1  = (unsigned short*)(ws + oH1);

  PrepArgs pa;
  pa.W[0]=W2cur;  pa.g[0]=g2c;     pa.Wt[0]=WtC2; pa.C[0]=C2;
  pa.W[1]=W2ref;  pa.g[1]=g2r;     pa.Wt[1]=WtR2; pa.C[1]=C2;
  pa.W[2]=convw2; pa.g[2]=nullptr; pa.Wt[2]=WtV2; pa.C[2]=C2;
  pa.W[3]=W1cur;  pa.g[3]=g1c;     pa.Wt[3]=WtC1; pa.C[3]=C1;
  pa.W[4]=W1ref;  pa.g[4]=g1r;     pa.Wt[4]=WtR1; pa.C[4]=C1;
  pa.W[5]=convw1; pa.g[5]=nullptr; pa.Wt[5]=WtV1; pa.C[5]=C1;
  prep_transpose<<<dim3(8,8,6), 256, 0, stream>>>(pa);

  ColArgs ca;
  ca.W[0]=W2cur; ca.g[0]=g2c; ca.b[0]=b2c; ca.extra[0]=nullptr; ca.ocs[0]=ColC2; ca.obs[0]=BiasC2; ca.C[0]=C2;
  ca.W[1]=W2ref; ca.g[1]=g2r; ca.b[1]=b2r; ca.extra[1]=bias2;   ca.ocs[1]=ColR2; ca.obs[1]=BiasR2; ca.C[1]=C2;
  ca.W[2]=W1cur; ca.g[2]=g1c; ca.b[2]=b1c; ca.extra[2]=nullptr; ca.ocs[2]=ColC1; ca.obs[2]=BiasC1; ca.C[2]=C1;
  ca.W[3]=W1ref; ca.g[3]=g1r; ca.b[3]=b1r; ca.extra[3]=bias1;   ca.ocs[3]=ColR1; ca.obs[3]=BiasR1; ca.C[3]=C1;
  prep_colsum<<<4, 256, 0, stream>>>(ca);

  float* out2 = (float*)d_out;
  float* out1 = out2 + (size_t)8*C2*HW2;

  k1_curproj<128><<<dim3(NP2/64, 1),    256, 0, stream>>>(x2, WtC2, ColC2, BiasC2, P2, CT2, NP2, HW2);
  k1_curproj<256><<<dim3(NP1/64, 2),    256, 0, stream>>>(x1, WtC1, ColC1, BiasC1, P1, CT1, NP1, HW1);
  k2_refproj<128><<<dim3(NP2/64, 1, 4), 256, 0, stream>>>(x2, WtR2, ColR2, BiasR2, P2, CT2, H2, NP2, HW2);
  k2_refproj<256><<<dim3(NP1/64, 2, 4), 256, 0, stream>>>(x1, WtR1, ColR1, BiasR1, P1, CT1, H1, NP1, HW1);
  k3_conv<128><<<dim3(NP2/64, 1),       256, 0, stream>>>(H2, WtV2, bns2, bnb2, out2, NP2, HW2);
  k3_conv<256><<<dim3(NP1/64, 2),       256, 0, stream>>>(H1, WtV1, bns1, bnb1, out1, NP1, HW1);
}

// Round 2
// 141.093 us; speedup vs baseline: 1.2706x; 1.2706x over previous
//
#include <hip/hip_runtime.h>
#include <stdint.h>

#define DI __device__ __forceinline__

typedef __attribute__((ext_vector_type(8))) short short8;
typedef __attribute__((ext_vector_type(4))) short short4v;
typedef __attribute__((ext_vector_type(4))) float f32x4;

DI float bf2f(unsigned short u){ union{unsigned int i; float f;} v; v.i = ((unsigned int)u)<<16; return v.f; }
DI unsigned short f2bf(float f){ union{float f; unsigned int i;} v; v.f=f; return (unsigned short)((v.i + 0x7fffu + ((v.i>>16)&1u))>>16); }
DI float siluf(float x){ return x/(1.f + __expf(-x)); }
DI f32x4 vzero(){ f32x4 z; z[0]=0.f;z[1]=0.f;z[2]=0.f;z[3]=0.f; return z; }
DI f32x4 vsplat(float x){ f32x4 z; z[0]=x;z[1]=x;z[2]=x;z[3]=x; return z; }

// ---------------- weight prep ----------------
struct PrepArgs {
  const float* W[6];
  const float* g[6];
  unsigned short* Wt[6];
  int C[6];
};

__global__ __launch_bounds__(256) void prep_transpose(PrepArgs a){
  int m = blockIdx.z;
  int C = a.C[m];
  int nt = C >> 5;
  if ((int)blockIdx.x >= nt || (int)blockIdx.y >= nt) return;
  __shared__ float tile[32][33];
  int col = threadIdx.x & 31;
  int rr  = threadIdx.x >> 5;
  const float* W = a.W[m];
  const float* g = a.g[m];
  #pragma unroll
  for (int p=0;p<4;++p){
    int r = rr + p*8;
    int cK = blockIdx.x*32 + r;
    int dN = blockIdx.y*32 + col;
    float v = W[(size_t)cK*C + dN];
    if (g) v *= g[cK];
    tile[r][col] = v;
  }
  __syncthreads();
  unsigned short* Wt = a.Wt[m];
  #pragma unroll
  for (int p=0;p<4;++p){
    int r = rr + p*8;
    int dN = blockIdx.y*32 + r;
    int cK = blockIdx.x*32 + col;
    Wt[(size_t)dN*C + cK] = f2bf(tile[col][r]);  // Wt[d][c] = g[c]*W[c][d]
  }
}

struct ColArgs {
  const float* W[4]; const float* g[4]; const float* b[4]; const float* extra[4];
  float* ocs[4]; float* obs[4]; int C[4];
};

// grid: (C_max/64, 4 matrices), 256 thr = 64 d-lanes x 4 c-groups.
// Coalesced 64-wide reads of W rows; LDS tree-reduce over the 4 groups.
__global__ __launch_bounds__(256) void prep_colsum(ColArgs a){
  int j = blockIdx.y;
  int C = a.C[j];
  int d0 = blockIdx.x * 64;
  if (d0 >= C) return;
  int dl = threadIdx.x & 63;
  int g  = threadIdx.x >> 6;
  int d  = d0 + dl;
  const float* W = a.W[j]; const float* gv = a.g[j]; const float* bv = a.b[j];
  float cs = 0.f, bs = 0.f;
  for (int c = g; c < C; c += 4){
    float gc = gv[c], bc = bv[c];
    float w = W[(size_t)c*C + d];
    cs += gc*w;
    bs += bc*w;
  }
  __shared__ float rcs[4][64], rbs[4][64];
  rcs[g][dl] = cs; rbs[g][dl] = bs;
  __syncthreads();
  if (threadIdx.x < 64){
    float c0 = rcs[0][dl]+rcs[1][dl]+rcs[2][dl]+rcs[3][dl];
    float b0 = rbs[0][dl]+rbs[1][dl]+rbs[2][dl]+rbs[3][dl];
    if (a.extra[j]) b0 += a.extra[j][d];
    a.ocs[j][d] = c0;
    a.obs[j][d] = b0;
  }
}

// ---------------- shared helpers ----------------
// LDS layout: row-major [rows][C] bf16, XOR-swizzled at 16B-chunk granularity:
// byte(row, chunk) = row*2C + ((chunk ^ (row&7))*16)

template<int C>
DI short8 readFrag(const short* S, int rowBase, int ks, int lane){
  int row = rowBase + (lane & 15);                 // rowBase multiple of 16 -> row&7 == lane&7
  int chunk = (ks*4 + ((lane>>4)&3)) ^ (lane & 7);
  return *(const short8*)((const char*)S + row*(2*C) + chunk*16);
}

// stage raw x (fp32, channel-major in global) into LDS bf16 [64 px][C], computing LN stats in fp32
template<int C>
DI void stageA_x(const float* __restrict__ xb, int strideC, short* As,
                 float* red, float* smean, float* srstd){
  int tid = threadIdx.x;
  int px = tid & 63, g = tid >> 6;            // px lane, channel-group
  float sum = 0.f, sq = 0.f;
  #pragma unroll
  for (int it=0; it<C/16; ++it){
    int cb = it*16 + g*4;
    float v0 = xb[(size_t)(cb+0)*strideC + px];
    float v1 = xb[(size_t)(cb+1)*strideC + px];
    float v2 = xb[(size_t)(cb+2)*strideC + px];
    float v3 = xb[(size_t)(cb+3)*strideC + px];
    sum += v0+v1+v2+v3;
    sq  += v0*v0+v1*v1+v2*v2+v3*v3;
    short4v pk;
    pk[0]=(short)f2bf(v0); pk[1]=(short)f2bf(v1); pk[2]=(short)f2bf(v2); pk[3]=(short)f2bf(v3);
    int chunk = cb >> 3;
    *(short4v*)((char*)As + px*(2*C) + ((chunk ^ (px&7))*16) + (cb&7)*2) = pk;
  }
  red[g*64 + px] = sum;
  red[256 + g*64 + px] = sq;
  __syncthreads();
  if (tid < 64){
    float s=0.f, q=0.f;
    #pragma unroll
    for (int gg=0; gg<4; ++gg){ s += red[gg*64+tid]; q += red[256+gg*64+tid]; }
    float m = s*(1.f/C);
    float var = fmaxf(q*(1.f/C) - m*m, 0.f);
    smean[tid] = m;
    srstd[tid] = rsqrtf(var + 1e-5f);
  }
  __syncthreads();
}

// copy bf16 row-major [ROWS][C] from global into swizzled LDS
template<int C, int ROWS>
DI void stageCopy(const unsigned short* __restrict__ src, short* dst){
  int tid = threadIdx.x;
  constexpr int CH = C/8;
  constexpr int IT = (ROWS*CH)/256;
  #pragma unroll
  for (int it=0; it<IT; ++it){
    int i = tid + it*256;
    int row = i / CH, ch = i % CH;
    short8 v = *(const short8*)(src + (size_t)row*C + ch*8);
    *(short8*)((char*)dst + row*(2*C) + ((ch ^ (row&7))*16)) = v;
  }
}

template<int C>
DI void mfmaLoop(const short* As, const short* Bs, f32x4 acc[2][4], int lane, int wr, int wc){
  #pragma unroll
  for (int ks=0; ks<C/32; ++ks){
    short8 a0 = readFrag<C>(As, wr*32 +  0, ks, lane);
    short8 a1 = readFrag<C>(As, wr*32 + 16, ks, lane);
    short8 b0 = readFrag<C>(Bs, wc*64 +  0, ks, lane);
    short8 b1 = readFrag<C>(Bs, wc*64 + 16, ks, lane);
    short8 b2 = readFrag<C>(Bs, wc*64 + 32, ks, lane);
    short8 b3 = readFrag<C>(Bs, wc*64 + 48, ks, lane);
    acc[0][0] = __builtin_amdgcn_mfma_f32_16x16x32_bf16(a0,b0,acc[0][0],0,0,0);
    acc[0][1] = __builtin_amdgcn_mfma_f32_16x16x32_bf16(a0,b1,acc[0][1],0,0,0);
    acc[0][2] = __builtin_amdgcn_mfma_f32_16x16x32_bf16(a0,b2,acc[0][2],0,0,0);
    acc[0][3] = __builtin_amdgcn_mfma_f32_16x16x32_bf16(a0,b3,acc[0][3],0,0,0);
    acc[1][0] = __builtin_amdgcn_mfma_f32_16x16x32_bf16(a1,b0,acc[1][0],0,0,0);
    acc[1][1] = __builtin_amdgcn_mfma_f32_16x16x32_bf16(a1,b1,acc[1][1],0,0,0);
    acc[1][2] = __builtin_amdgcn_mfma_f32_16x16x32_bf16(a1,b2,acc[1][2],0,0,0);
    acc[1][3] = __builtin_amdgcn_mfma_f32_16x16x32_bf16(a1,b3,acc[1][3],0,0,0);
  }
}

// ---------------- K1: cur_proj = LN(cur) @ Wcur ----------------
template<int C>
__global__ __launch_bounds__(256) void k1_curproj(
    const float* __restrict__ x, const unsigned short* __restrict__ Wt,
    const float* __restrict__ colsum, const float* __restrict__ bias,
    unsigned short* __restrict__ Pout, unsigned short* __restrict__ curT,
    int Npix, int HW){
  constexpr int T = 5;
  __shared__ __align__(16) short As[64*C];
  __shared__ __align__(16) short Bs[128*C];
  __shared__ float red[512];
  __shared__ float smean[64], srstd[64];

  int n0 = blockIdx.y*128;
  int px0 = blockIdx.x*64;
  int b = px0 / HW, hw0 = px0 % HW;
  const float* xb = x + ((size_t)b*C*T + (T-1))*HW + hw0;   // c=0, t=T-1

  stageCopy<C,128>(Wt + (size_t)n0*C, Bs);
  stageA_x<C>(xb, T*HW, As, red, smean, srstd);

  int tid = threadIdx.x, lane = tid&63, wid = tid>>6, wr = wid>>1, wc = wid&1, hi = lane>>4;
  f32x4 acc[2][4];
  #pragma unroll
  for (int i=0;i<2;++i)
    #pragma unroll
    for (int j=0;j<4;++j) acc[i][j] = vzero();
  mfmaLoop<C>(As, Bs, acc, lane, wr, wc);

  if (n0 == 0){  // write transposed raw cur (bf16) for K2's residual
    constexpr int CH = C/8;
    #pragma unroll
    for (int it=0; it<(64*CH)/256; ++it){
      int i = tid + it*256;
      int row = i/CH, ch = i%CH;
      short8 v = *(const short8*)((const char*)As + row*(2*C) + ((ch ^ (row&7))*16));
      *(short8*)(curT + (size_t)(px0+row)*C + ch*8) = v;
    }
  }

  #pragma unroll
  for (int nf=0; nf<4; ++nf){
    int d = n0 + wc*64 + nf*16 + (lane&15);
    float cs = colsum[d], bi = bias[d];
    #pragma unroll
    for (int mf=0; mf<2; ++mf){
      #pragma unroll
      for (int r=0; r<4; ++r){
        int pl = wr*32 + mf*16 + hi*4 + r;
        float P = srstd[pl]*(acc[mf][nf][r] - smean[pl]*cs) + bi;
        Pout[(size_t)(px0+pl)*C + d] = f2bf(P);
      }
    }
  }
}

// ---------------- K2: h = cur + silu(cur_proj + LN(ref_t)@Wref + bf) ----------------
template<int C>
__global__ __launch_bounds__(256) void k2_refproj(
    const float* __restrict__ x, const unsigned short* __restrict__ Wt,
    const float* __restrict__ colsum, const float* __restrict__ biasRf,
    const unsigned short* __restrict__ Pcur, const unsigned short* __restrict__ curT,
    unsigned short* __restrict__ hout, int Npix, int HW){
  constexpr int T = 5;
  __shared__ __align__(16) short As[64*C];
  __shared__ __align__(16) short Bs[128*C];
  __shared__ float red[512];
  __shared__ float smean[64], srstd[64];

  int n0 = blockIdx.y*128;
  int px0 = blockIdx.x*64;
  int t = blockIdx.z;
  int b = px0 / HW, hw0 = px0 % HW;
  const float* xb = x + ((size_t)b*C*T + t)*HW + hw0;

  stageCopy<C,128>(Wt + (size_t)n0*C, Bs);
  stageA_x<C>(xb, T*HW, As, red, smean, srstd);

  int tid = threadIdx.x, lane = tid&63, wid = tid>>6, wr = wid>>1, wc = wid&1, hi = lane>>4;
  f32x4 acc[2][4];
  #pragma unroll
  for (int i=0;i<2;++i)
    #pragma unroll
    for (int j=0;j<4;++j) acc[i][j] = vzero();
  mfmaLoop<C>(As, Bs, acc, lane, wr, wc);

  #pragma unroll
  for (int nf=0; nf<4; ++nf){
    int d = n0 + wc*64 + nf*16 + (lane&15);
    float cs = colsum[d], bi = biasRf[d];
    #pragma unroll
    for (int mf=0; mf<2; ++mf){
      #pragma unroll
      for (int r=0; r<4; ++r){
        int pl = wr*32 + mf*16 + hi*4 + r;
        size_t idx = (size_t)(px0+pl)*C + d;
        float pre = srstd[pl]*(acc[mf][nf][r] - smean[pl]*cs) + bi + bf2f(Pcur[idx]);
        float h = bf2f(curT[idx]) + siluf(pre);
        hout[(size_t)t*Npix*C + idx] = f2bf(h);
      }
    }
  }
}

// ---------------- K3: y_t = silu((h_t @ convw)*bns + bnb); out = max_t + mean_t ----------------
template<int C>
__global__ __launch_bounds__(256) void k3_conv(
    const unsigned short* __restrict__ h, const unsigned short* __restrict__ WtV,
    const float* __restrict__ bns, const float* __restrict__ bnb,
    float* __restrict__ out, int Npix, int HW){
  constexpr int PB = 133;
  constexpr int AsBytes = 64*C*2;
  constexpr int PoolBytes = 64*PB*4;
  constexpr int U = (AsBytes > PoolBytes) ? AsBytes : PoolBytes;
  __shared__ __align__(16) char uni[U];
  __shared__ __align__(16) short Bs[128*C];
  short* As = (short*)uni;
  float* pool = (float*)uni;

  int n0 = blockIdx.y*128;
  int px0 = blockIdx.x*64;
  int b = px0 / HW, hw0 = px0 % HW;
  int tid = threadIdx.x, lane = tid&63, wid = tid>>6, wr = wid>>1, wc = wid&1, hi = lane>>4;

  stageCopy<C,128>(WtV + (size_t)n0*C, Bs);

  f32x4 mx[2][4], sm[2][4];
  #pragma unroll
  for (int i=0;i<2;++i)
    #pragma unroll
    for (int j=0;j<4;++j){ mx[i][j] = vsplat(-3.0e38f); sm[i][j] = vzero(); }

  for (int t=0; t<4; ++t){
    __syncthreads();                      // t=0: Bs ready; t>0: prev reads of As done
    stageCopy<C,64>(h + ((size_t)t*Npix + px0)*C, As);
    __syncthreads();
    f32x4 acc[2][4];
    #pragma unroll
    for (int i=0;i<2;++i)
      #pragma unroll
      for (int j=0;j<4;++j) acc[i][j] = vzero();
    mfmaLoop<C>(As, Bs, acc, lane, wr, wc);
    #pragma unroll
    for (int nf=0; nf<4; ++nf){
      int d = n0 + wc*64 + nf*16 + (lane&15);
      float s_ = bns[d], b_ = bnb[d];
      #pragma unroll
      for (int mf=0; mf<2; ++mf){
        #pragma unroll
        for (int r=0; r<4; ++r){
          float y = siluf(acc[mf][nf][r]*s_ + b_);
          mx[mf][nf][r] = fmaxf(mx[mf][nf][r], y);
          sm[mf][nf][r] += y;
        }
      }
    }
  }

  __syncthreads();   // all MFMA reads of As done; reuse as pool buffer
  #pragma unroll
  for (int nf=0; nf<4; ++nf){
    int dl = wc*64 + nf*16 + (lane&15);
    #pragma unroll
    for (int mf=0; mf<2; ++mf){
      #pragma unroll
      for (int r=0; r<4; ++r){
        int pl = wr*32 + mf*16 + hi*4 + r;
        pool[pl*PB + dl] = mx[mf][nf][r] + 0.25f*sm[mf][nf][r];
      }
    }
  }
  __syncthreads();

  #pragma unroll
  for (int it=0; it<8; ++it){            // 64px * 128d / (256 thr * 4 floats)
    int i = tid + it*256;
    int dl = i >> 4;
    int pq = (i & 15) * 4;
    f32x4 vv;
    #pragma unroll
    for (int k=0;k<4;++k) vv[k] = pool[(pq+k)*PB + dl];
    *(f32x4*)(out + (size_t)(b*C + n0 + dl)*HW + hw0 + pq) = vv;
  }
}

// ---------------- host ----------------
extern "C" void kernel_launch(void* const* d_in, const int* in_sizes, int n_in,
                              void* d_out, int out_size, void* d_ws, size_t ws_size,
                              hipStream_t stream) {
  (void)in_sizes; (void)n_in; (void)out_size; (void)ws_size;
  const float* x2    = (const float*)d_in[0];
  const float* x1    = (const float*)d_in[1];
  const float* g2c   = (const float*)d_in[3];
  const float* b2c   = (const float*)d_in[4];
  const float* g2r   = (const float*)d_in[5];
  const float* b2r   = (const float*)d_in[6];
  const float* W2cur = (const float*)d_in[7];
  const float* W2ref = (const float*)d_in[8];
  const float* bias2 = (const float*)d_in[9];
  const float* convw2= (const float*)d_in[10];
  const float* bns2  = (const float*)d_in[11];
  const float* bnb2  = (const float*)d_in[12];
  const float* g1c   = (const float*)d_in[13];
  const float* b1c   = (const float*)d_in[14];
  const float* g1r   = (const float*)d_in[15];
  const float* b1r   = (const float*)d_in[16];
  const float* W1cur = (const float*)d_in[17];
  const float* W1ref = (const float*)d_in[18];
  const float* bias1 = (const float*)d_in[19];
  const float* convw1= (const float*)d_in[20];
  const float* bns1  = (const float*)d_in[21];
  const float* bnb1  = (const float*)d_in[22];

  const int C2 = 128, C1 = 256;
  const int NP2 = 8*64*64, NP1 = 8*32*32;   // 32768, 8192
  const int HW2 = 4096, HW1 = 1024;

  char* ws = (char*)d_ws;
  size_t off = 0;
  auto alloc = [&](size_t bytes){ size_t o = off; off = (off + bytes + 255) & ~(size_t)255; return o; };
  size_t oWtC2 = alloc((size_t)C2*C2*2), oWtR2 = alloc((size_t)C2*C2*2), oWtV2 = alloc((size_t)C2*C2*2);
  size_t oWtC1 = alloc((size_t)C1*C1*2), oWtR1 = alloc((size_t)C1*C1*2), oWtV1 = alloc((size_t)C1*C1*2);
  size_t oColC2 = alloc(C2*4), oBiasC2 = alloc(C2*4), oColR2 = alloc(C2*4), oBiasR2 = alloc(C2*4);
  size_t oColC1 = alloc(C1*4), oBiasC1 = alloc(C1*4), oColR1 = alloc(C1*4), oBiasR1 = alloc(C1*4);
  size_t oP2  = alloc((size_t)NP2*C2*2);
  size_t oCT2 = alloc((size_t)NP2*C2*2);
  size_t oH2  = alloc((size_t)4*NP2*C2*2);
  size_t oP1  = alloc((size_t)NP1*C1*2);
  size_t oCT1 = alloc((size_t)NP1*C1*2);
  size_t oH1  = alloc((size_t)4*NP1*C1*2);

  unsigned short* WtC2 = (unsigned short*)(ws + oWtC2);
  unsigned short* WtR2 = (unsigned short*)(ws + oWtR2);
  unsigned short* WtV2 = (unsigned short*)(ws + oWtV2);
  unsigned short* WtC1 = (unsigned short*)(ws + oWtC1);
  unsigned short* WtR1 = (unsigned short*)(ws + oWtR1);
  unsigned short* WtV1 = (unsigned short*)(ws + oWtV1);
  float* ColC2 = (float*)(ws + oColC2); float* BiasC2 = (float*)(ws + oBiasC2);
  float* ColR2 = (float*)(ws + oColR2); float* BiasR2 = (float*)(ws + oBiasR2);
  float* ColC1 = (float*)(ws + oColC1); float* BiasC1 = (float*)(ws + oBiasC1);
  float* ColR1 = (float*)(ws + oColR1); float* BiasR1 = (float*)(ws + oBiasR1);
  unsigned short* P2  = (unsigned short*)(ws + oP2);
  unsigned short* CT2 = (unsigned short*)(ws + oCT2);
  unsigned short* H2  = (unsigned short*)(ws + oH2);
  unsigned short* P1  = (unsigned short*)(ws + oP1);
  unsigned short* CT1 = (unsigned short*)(ws + oCT1);
  unsigned short* H1  = (unsigned short*)(ws + oH1);

  PrepArgs pa;
  pa.W[0]=W2cur;  pa.g[0]=g2c;     pa.Wt[0]=WtC2; pa.C[0]=C2;
  pa.W[1]=W2ref;  pa.g[1]=g2r;     pa.Wt[1]=WtR2; pa.C[1]=C2;
  pa.W[2]=convw2; pa.g[2]=nullptr; pa.Wt[2]=WtV2; pa.C[2]=C2;
  pa.W[3]=W1cur;  pa.g[3]=g1c;     pa.Wt[3]=WtC1; pa.C[3]=C1;
  pa.W[4]=W1ref;  pa.g[4]=g1r;     pa.Wt[4]=WtR1; pa.C[4]=C1;
  pa.W[5]=convw1; pa.g[5]=nullptr; pa.Wt[5]=WtV1; pa.C[5]=C1;
  prep_transpose<<<dim3(8,8,6), 256, 0, stream>>>(pa);

  ColArgs ca;
  ca.W[0]=W2cur; ca.g[0]=g2c; ca.b[0]=b2c; ca.extra[0]=nullptr; ca.ocs[0]=ColC2; ca.obs[0]=BiasC2; ca.C[0]=C2;
  ca.W[1]=W2ref; ca.g[1]=g2r; ca.b[1]=b2r; ca.extra[1]=bias2;   ca.ocs[1]=ColR2; ca.obs[1]=BiasR2; ca.C[1]=C2;
  ca.W[2]=W1cur; ca.g[2]=g1c; ca.b[2]=b1c; ca.extra[2]=nullptr; ca.ocs[2]=ColC1; ca.obs[2]=BiasC1; ca.C[2]=C1;
  ca.W[3]=W1ref; ca.g[3]=g1r; ca.b[3]=b1r; ca.extra[3]=bias1;   ca.ocs[3]=ColR1; ca.obs[3]=BiasR1; ca.C[3]=C1;
  prep_colsum<<<dim3(4, 4), 256, 0, stream>>>(ca);

  float* out2 = (float*)d_out;
  float* out1 = out2 + (size_t)8*C2*HW2;

  k1_curproj<128><<<dim3(NP2/64, 1),    256, 0, stream>>>(x2, WtC2, ColC2, BiasC2, P2, CT2, NP2, HW2);
  k1_curproj<256><<<dim3(NP1/64, 2),    256, 0, stream>>>(x1, WtC1, ColC1, BiasC1, P1, CT1, NP1, HW1);
  k2_refproj<128><<<dim3(NP2/64, 1, 4), 256, 0, stream>>>(x2, WtR2, ColR2, BiasR2, P2, CT2, H2, NP2, HW2);
  k2_refproj<256><<<dim3(NP1/64, 2, 4), 256, 0, stream>>>(x1, WtR1, ColR1, BiasR1, P1, CT1, H1, NP1, HW1);
  k3_conv<128><<<dim3(NP2/64, 1),       256, 0, stream>>>(H2, WtV2, bns2, bnb2, out2, NP2, HW2);
  k3_conv<256><<<dim3(NP1/64, 2),       256, 0, stream>>>(H1, WtV1, bns1, bnb1, out1, NP1, HW1);
}